// Round 2
// baseline (26355.386 us; speedup 1.0000x reference)
//
#include <hip/hip_runtime.h>
#include <hip/hip_bf16.h>
#include <math.h>

#define SEQ   1570
#define NB    4
#define NF    8
#define NT    196
#define NH    8
#define DM    512
#define MR    (NB*SEQ)   // 6280 rows

// ---------------------------------------------------------------------------
// Rotary tables: frame (8x64 sin/cos) and image (196x64 sin/cos)
// ---------------------------------------------------------------------------
__global__ void build_rot_k(float* fsin, float* fcos, float* isin, float* icos)
{
    int tid = blockIdx.x * blockDim.x + threadIdx.x;
    if (tid < NF * 32) {
        int fi = tid >> 5, i = tid & 31;
        float inv = powf(10000.f, -(2.f * i) / 64.f);
        float v = fi * inv;
        float s = sinf(v), c = cosf(v);
        fsin[fi*64 + 2*i] = s; fsin[fi*64 + 2*i + 1] = s;
        fcos[fi*64 + 2*i] = c; fcos[fi*64 + 2*i + 1] = c;
    }
    if (tid < NT * 32) {
        int t = tid >> 5, i = tid & 31;
        int hi = t / 14, wi = t % 14;
        const float PI = 3.14159265358979323846f;
        float v;
        if (i < 16) {
            float scale = 1.f + 4.f * i / 15.f;          // linspace(1, 5, 16)
            v = (-1.f + 2.f * hi / 13.f) * scale * PI;   // linspace(-1,1,14)
        } else {
            float scale = 1.f + 4.f * (i - 16) / 15.f;
            v = (-1.f + 2.f * wi / 13.f) * scale * PI;
        }
        float s = sinf(v), c = cosf(v);
        isin[t*64 + 2*i] = s; isin[t*64 + 2*i + 1] = s;
        icos[t*64 + 2*i] = c; icos[t*64 + 2*i + 1] = c;
    }
}

// ---------------------------------------------------------------------------
// Patchify: video (4,8,3,224,224) f32 -> VP (4,1568,768) f32
// vp[b, fi*196 + hi*14 + wi, (pr*16+pc)*3 + ch] = video[b, fi, ch, hi*16+pr, wi*16+pc]
// ---------------------------------------------------------------------------
__global__ void patch_gather_k(const float* __restrict__ video, float* __restrict__ VP)
{
    int idx = blockIdx.x * blockDim.x + threadIdx.x;
    if (idx >= NB * NF * NT * 768) return;
    int kk  = idx % 768;
    int row = (idx / 768) % (NF * NT);
    int b   = idx / (768 * NF * NT);
    int ch = kk % 3, pp = kk / 3;
    int pr = pp >> 4, pc = pp & 15;
    int fi = row / NT, t = row % NT;
    int hi = t / 14, wi = t % 14;
    size_t src = ((((size_t)b * NF + fi) * 3 + ch) * 224 + (hi*16 + pr)) * 224 + (wi*16 + pc);
    VP[idx] = video[src];
}

// ---------------------------------------------------------------------------
// cls token row + action-angle row
// ---------------------------------------------------------------------------
__global__ void init_special_k(float* X, const float* __restrict__ cls,
                               const float* __restrict__ aa_w,
                               const float* __restrict__ aa_W,
                               const float* __restrict__ aa_b)
{
    int idx = blockIdx.x * blockDim.x + threadIdx.x;
    if (idx >= NB * DM) return;
    int b = idx >> 9, d = idx & 511;
    X[(size_t)b * SEQ * DM + d] = cls[d];
    float acc = aa_b[d];
    for (int i = 0; i < 18; ++i) acc += aa_w[b*18 + i] * aa_W[i*DM + d];
    X[((size_t)b * SEQ + 1) * DM + d] = acc;
}

// ---------------------------------------------------------------------------
// Generic GEMM: C[M,N] = A[M,K](f32) * B[K,N](f32) (+bias f32) (+resid f32)
// 64x64 tile, BK=16, 256 threads, 4x4 per thread. Correctness-first SGEMM.
// ---------------------------------------------------------------------------
__global__ __launch_bounds__(256) void gemm_f32(
    const float* __restrict__ A, const float* __restrict__ B,
    float* C, const float* __restrict__ bias, const float* resid,
    int M, int N, int K)
{
    __shared__ float As[16][65];
    __shared__ float Bs[16][64];
    int bm = blockIdx.y, bn = blockIdx.x;
    int tid = threadIdx.x;
    int tx = tid & 15, ty = tid >> 4;
    int row0 = bm * 64, col0 = bn * 64;
    float acc[4][4] = {};
    for (int k0 = 0; k0 < K; k0 += 16) {
        #pragma unroll
        for (int l = 0; l < 4; ++l) {
            int i = tid + l * 256;
            int m = i >> 4, kk = i & 15;
            int gm = row0 + m;
            As[kk][m] = (gm < M) ? A[(size_t)gm * K + k0 + kk] : 0.f;
        }
        #pragma unroll
        for (int l = 0; l < 4; ++l) {
            int i = tid + l * 256;
            int kk = i >> 6, nn = i & 63;
            Bs[kk][nn] = B[(size_t)(k0 + kk) * N + col0 + nn];
        }
        __syncthreads();
        #pragma unroll
        for (int kk = 0; kk < 16; ++kk) {
            float ar[4], br[4];
            #pragma unroll
            for (int i = 0; i < 4; ++i) ar[i] = As[kk][ty*4 + i];
            #pragma unroll
            for (int j = 0; j < 4; ++j) br[j] = Bs[kk][tx*4 + j];
            #pragma unroll
            for (int i = 0; i < 4; ++i)
                #pragma unroll
                for (int j = 0; j < 4; ++j) acc[i][j] += ar[i] * br[j];
        }
        __syncthreads();
    }
    #pragma unroll
    for (int i = 0; i < 4; ++i) {
        int gm = row0 + ty*4 + i;
        if (gm >= M) continue;
        #pragma unroll
        for (int j = 0; j < 4; ++j) {
            int gn = col0 + tx*4 + j;
            float v = acc[i][j];
            if (bias)  v += bias[gn];
            size_t off = (size_t)gm * N + gn;
            if (resid) v += resid[off];
            C[off] = v;
        }
    }
}

// ---------------------------------------------------------------------------
// LayerNorm over rows of 512
// ---------------------------------------------------------------------------
__global__ __launch_bounds__(256) void layernorm_k(
    const float* __restrict__ X, float* __restrict__ XN,
    const float* __restrict__ g, const float* __restrict__ b)
{
    int row = blockIdx.x, tid = threadIdx.x;
    const float* x = X + (size_t)row * DM;
    float v0 = x[tid], v1 = x[tid + 256];
    __shared__ float r1[256], r2[256];
    r1[tid] = v0 + v1;
    r2[tid] = v0*v0 + v1*v1;
    __syncthreads();
    for (int off = 128; off > 0; off >>= 1) {
        if (tid < off) { r1[tid] += r1[tid+off]; r2[tid] += r2[tid+off]; }
        __syncthreads();
    }
    float mean = r1[0] * (1.f / DM);
    float var  = r2[0] * (1.f / DM) - mean * mean;
    float inv  = rsqrtf(var + 1e-5f);
    float* y = XN + (size_t)row * DM;
    y[tid]       = (v0 - mean) * inv * g[tid]       + b[tid];
    y[tid + 256] = (v1 - mean) * inv * g[tid + 256] + b[tid + 256];
}

// ---------------------------------------------------------------------------
// Special-token attention: q rows 0,1 (scaled) over all 1570 unrotated k/v.
// One block per (b,h). Must run BEFORE in-place RoPE.
// ---------------------------------------------------------------------------
__global__ __launch_bounds__(128) void attn_special_k(
    const float* __restrict__ QKV, float* __restrict__ AO)
{
    int bh = blockIdx.x;
    int b = bh >> 3, h = bh & 7;
    int tid = threadIdx.x;
    __shared__ float qsp[2][64];
    __shared__ float sc[2][SEQ];
    {
        int qi = tid >> 6, d = tid & 63;
        qsp[qi][d] = QKV[((size_t)(b*SEQ + qi))*1536 + h*64 + d] * 0.125f;
    }
    __syncthreads();
    for (int i = tid; i < 2*SEQ; i += 128) {
        int qi = i & 1, kj = i >> 1;
        const float* kp = QKV + ((size_t)(b*SEQ + kj))*1536 + 512 + h*64;
        float s = 0.f;
        #pragma unroll
        for (int d = 0; d < 64; ++d) s += qsp[qi][d] * kp[d];
        sc[qi][kj] = s;
    }
    __syncthreads();
    if (tid < 2) {
        float mx = -1e30f;
        for (int k = 0; k < SEQ; ++k) mx = fmaxf(mx, sc[tid][k]);
        float sum = 0.f;
        for (int k = 0; k < SEQ; ++k) { float e = expf(sc[tid][k] - mx); sc[tid][k] = e; sum += e; }
        float inv = 1.f / sum;
        for (int k = 0; k < SEQ; ++k) sc[tid][k] *= inv;
    }
    __syncthreads();
    int qi = tid >> 6, d = tid & 63;
    float acc = 0.f;
    for (int k = 0; k < SEQ; ++k)
        acc += sc[qi][k] * QKV[((size_t)(b*SEQ + k))*1536 + 1024 + h*64 + d];
    AO[((size_t)(b*SEQ + qi))*DM + h*64 + d] = acc;
}

// ---------------------------------------------------------------------------
// In-place RoPE on q and k for token rows >= 2.
// mode 0 (time):  table index = frame  = (s-2)/196
// mode 1 (space): table index = token  = (s-2)%196
// ---------------------------------------------------------------------------
__global__ void rope_k(float* QKV, const float* __restrict__ sn,
                       const float* __restrict__ cs, int mode)
{
    int idx = blockIdx.x * blockDim.x + threadIdx.x;   // 4*1568*8*32
    if (idx >= NB * NF * NT * NH * 32) return;
    int p = idx & 31;
    int h = (idx >> 5) & 7;
    int t = (idx >> 8) % (NF * NT);
    int b = (idx >> 8) / (NF * NT);
    int ri = (mode == 0) ? (t / NT) : (t % NT);
    float c = cs[ri*64 + 2*p], s = sn[ri*64 + 2*p];
    size_t base = ((size_t)(b*SEQ + 2 + t)) * 1536 + h*64 + 2*p;
    float x0 = QKV[base], x1 = QKV[base + 1];
    QKV[base]     = x0 * c - x1 * s;
    QKV[base + 1] = x1 * c + x0 * s;
    base += 512;   // k
    x0 = QKV[base]; x1 = QKV[base + 1];
    QKV[base]     = x0 * c - x1 * s;
    QKV[base + 1] = x1 * c + x0 * s;
}

// ---------------------------------------------------------------------------
// Grouped attention (after RoPE). Key index kj<2 -> unrotated special rows 0,1.
// mode 0: group g = bh*196 + j,  L=8   queries (frames),  S=10
// mode 1: group g = bh*8 + fi,   L=196 queries (tokens),  S=198
// Block = (group, 16-query tile), 256 threads.
// ---------------------------------------------------------------------------
__global__ __launch_bounds__(256) void attn_main_k(
    const float* __restrict__ QKV, float* __restrict__ AO, int mode)
{
    __shared__ float qs[16][68];
    __shared__ float ks[64][68];
    __shared__ float sc[16][208];
    int g = blockIdx.x, qt = blockIdx.y, tid = threadIdx.x;
    int bh, jj, fi, L, S;
    if (mode == 0) { bh = g / NT; jj = g % NT; fi = 0; L = NF; S = NF + 2; }
    else           { bh = g / NF; fi = g % NF; jj = 0; L = NT; S = NT + 2; }
    int b = bh >> 3, h = bh & 7;
    int q0 = qt * 16;

    for (int i = tid; i < 16*64; i += 256) {
        int qi = i >> 6, d = i & 63;
        int ql = q0 + qi;
        float v = 0.f;
        if (ql < L) {
            int s = (mode == 0) ? (2 + ql*NT + jj) : (2 + fi*NT + ql);
            v = QKV[((size_t)(b*SEQ + s))*1536 + h*64 + d] * 0.125f;
        }
        qs[qi][d] = v;
    }
    __syncthreads();

    for (int kb = 0; kb < S; kb += 64) {
        int kc = min(64, S - kb);
        for (int i = tid; i < 64*64; i += 256) {
            int r = i >> 6, d = i & 63;
            float v = 0.f;
            int kj = kb + r;
            if (kj < S) {
                int s = (kj < 2) ? kj
                        : ((mode == 0) ? (2 + (kj-2)*NT + jj) : (2 + fi*NT + (kj-2)));
                v = QKV[((size_t)(b*SEQ + s))*1536 + 512 + h*64 + d];
            }
            ks[r][d] = v;
        }
        __syncthreads();
        for (int i = tid; i < 16*64; i += 256) {
            int qi = i & 15, r = i >> 4;
            if (r < kc) {
                float s = 0.f;
                #pragma unroll
                for (int d = 0; d < 64; ++d) s += qs[qi][d] * ks[r][d];
                sc[qi][kb + r] = s;
            }
        }
        __syncthreads();
    }

    if (tid < 16) {
        float mx = -1e30f;
        for (int k = 0; k < S; ++k) mx = fmaxf(mx, sc[tid][k]);
        float sum = 0.f;
        for (int k = 0; k < S; ++k) { float e = expf(sc[tid][k] - mx); sc[tid][k] = e; sum += e; }
        float inv = 1.f / sum;
        for (int k = 0; k < S; ++k) sc[tid][k] *= inv;
    }
    __syncthreads();

    float acc[4] = {0.f, 0.f, 0.f, 0.f};
    int qi = tid >> 4, d0 = (tid & 15) * 4;
    for (int kb = 0; kb < S; kb += 64) {
        int kc = min(64, S - kb);
        for (int i = tid; i < 64*64; i += 256) {
            int r = i >> 6, d = i & 63;
            float v = 0.f;
            int kj = kb + r;
            if (kj < S) {
                int s = (kj < 2) ? kj
                        : ((mode == 0) ? (2 + (kj-2)*NT + jj) : (2 + fi*NT + (kj-2)));
                v = QKV[((size_t)(b*SEQ + s))*1536 + 1024 + h*64 + d];
            }
            ks[r][d] = v;
        }
        __syncthreads();
        for (int r = 0; r < kc; ++r) {
            float p = sc[qi][kb + r];
            #pragma unroll
            for (int c = 0; c < 4; ++c) acc[c] += p * ks[r][d0 + c];
        }
        __syncthreads();
    }
    int ql = q0 + qi;
    if (ql < L) {
        int s = (mode == 0) ? (2 + ql*NT + jj) : (2 + fi*NT + ql);
        size_t off = ((size_t)(b*SEQ + s))*DM + h*64 + d0;
        #pragma unroll
        for (int c = 0; c < 4; ++c) AO[off + c] = acc[c];
    }
}

// ---------------------------------------------------------------------------
// GEGLU: B2[m,i] = B1[m,i] * gelu_exact(B1[m, 2048+i])
// ---------------------------------------------------------------------------
__global__ void geglu_k(const float* __restrict__ B1, float* __restrict__ B2)
{
    int idx = blockIdx.x * blockDim.x + threadIdx.x;
    if (idx >= MR * 2048) return;
    int m = idx / 2048;
    int i = idx % 2048;
    float a  = B1[(size_t)m * 4096 + i];
    float gg = B1[(size_t)m * 4096 + 2048 + i];
    float gl = 0.5f * gg * (1.f + erff(gg * 0.70710678118654752f));
    B2[idx] = a * gl;
}

// ---------------------------------------------------------------------------
// Final head: LN(x[:,0]) @ out_W (512,2) + out_b -> f32 out (4,2)
// ---------------------------------------------------------------------------
__global__ __launch_bounds__(256) void final_head_k(
    const float* __restrict__ X, const float* __restrict__ g, const float* __restrict__ bt,
    const float* __restrict__ W, const float* __restrict__ bo, float* __restrict__ out)
{
    int b = blockIdx.x, tid = threadIdx.x;
    const float* x = X + (size_t)b * SEQ * DM;
    float v0 = x[tid], v1 = x[tid + 256];
    __shared__ float r1[256], r2[256];
    r1[tid] = v0 + v1;
    r2[tid] = v0*v0 + v1*v1;
    __syncthreads();
    for (int off = 128; off > 0; off >>= 1) {
        if (tid < off) { r1[tid] += r1[tid+off]; r2[tid] += r2[tid+off]; }
        __syncthreads();
    }
    float mean = r1[0] * (1.f / DM);
    float var  = r2[0] * (1.f / DM) - mean * mean;
    float inv  = rsqrtf(var + 1e-5f);
    float xn0 = (v0 - mean) * inv * g[tid]       + bt[tid];
    float xn1 = (v1 - mean) * inv * g[tid + 256] + bt[tid + 256];
    __syncthreads();
    r1[tid] = xn0 * W[tid*2]     + xn1 * W[(tid+256)*2];
    r2[tid] = xn0 * W[tid*2 + 1] + xn1 * W[(tid+256)*2 + 1];
    __syncthreads();
    for (int off = 128; off > 0; off >>= 1) {
        if (tid < off) { r1[tid] += r1[tid+off]; r2[tid] += r2[tid+off]; }
        __syncthreads();
    }
    if (tid == 0) {
        out[b*2 + 0] = r1[0] + bo[0];
        out[b*2 + 1] = r2[0] + bo[1];
    }
}

// ---------------------------------------------------------------------------
extern "C" void kernel_launch(void* const* d_in, const int* in_sizes, int n_in,
                              void* d_out, int out_size, void* d_ws, size_t ws_size,
                              hipStream_t stream)
{
    const float* video    = (const float*)d_in[0];
    const float* aa_w     = (const float*)d_in[1];
    const float* patch_W  = (const float*)d_in[2];
    const float* patch_b  = (const float*)d_in[3];
    const float* cls_tok  = (const float*)d_in[4];
    const float* aa_W     = (const float*)d_in[5];
    const float* aa_b     = (const float*)d_in[6];
    const float* ln_t_g   = (const float*)d_in[7];
    const float* ln_t_b   = (const float*)d_in[8];
    const float* t_qkv    = (const float*)d_in[9];
    const float* t_outW   = (const float*)d_in[10];
    const float* t_outb   = (const float*)d_in[11];
    const float* ln_s_g   = (const float*)d_in[12];
    const float* ln_s_b   = (const float*)d_in[13];
    const float* s_qkv    = (const float*)d_in[14];
    const float* s_outW   = (const float*)d_in[15];
    const float* s_outb   = (const float*)d_in[16];
    const float* ln_f_g   = (const float*)d_in[17];
    const float* ln_f_b   = (const float*)d_in[18];
    const float* ff_W1    = (const float*)d_in[19];
    const float* ff_b1    = (const float*)d_in[20];
    const float* ff_W2    = (const float*)d_in[21];
    const float* ff_b2    = (const float*)d_in[22];
    const float* out_ln_g = (const float*)d_in[23];
    const float* out_ln_b = (const float*)d_in[24];
    const float* out_W    = (const float*)d_in[25];
    const float* out_b    = (const float*)d_in[26];

    float* ws = (float*)d_ws;
    size_t o = 0;
    float* X    = ws + o; o += (size_t)MR * DM;        // residual stream
    float* XN   = ws + o; o += (size_t)MR * DM;        // LN output
    float* QKV  = ws + o; o += (size_t)MR * 3 * DM;    // qkv
    float* AO   = ws + o; o += (size_t)MR * DM;        // attention out (pre-proj)
    float* B1   = ws + o; o += (size_t)MR * 8 * DM;    // ff hidden 4096 (also VP scratch)
    float* B2   = ws + o; o += (size_t)MR * 4 * DM;    // geglu out 2048
    float* fsin = ws + o; o += 8 * 64;
    float* fcos = ws + o; o += 8 * 64;
    float* isin = ws + o; o += 196 * 64;
    float* icos = ws + o; o += 196 * 64;
    float* VP = B1;                                    // (4,1568,768) fp32

    auto gemm = [&](const float* A, const float* B, float* C, const float* bias,
                    const float* resid, int M, int N, int K) {
        dim3 grid(N / 64, (M + 63) / 64);
        gemm_f32<<<grid, 256, 0, stream>>>(A, B, C, bias, resid, M, N, K);
    };

    // Rotary tables
    build_rot_k<<<25, 256, 0, stream>>>(fsin, fcos, isin, icos);

    // Patchify + token embedding
    patch_gather_k<<<(NB*NF*NT*768 + 255)/256, 256, 0, stream>>>(video, VP);
    init_special_k<<<(NB*DM + 255)/256, 256, 0, stream>>>(X, cls_tok, aa_w, aa_W, aa_b);
    for (int b = 0; b < NB; ++b) {
        gemm(VP + (size_t)b * NF * NT * 768, patch_W,
             X + ((size_t)b * SEQ + 2) * DM, patch_b, nullptr,
             NF * NT, DM, 768);
    }

    for (int l = 0; l < 12; ++l) {
        // ---- time attention ----
        layernorm_k<<<MR, 256, 0, stream>>>(X, XN, ln_t_g + l*DM, ln_t_b + l*DM);
        gemm(XN, t_qkv + (size_t)l*DM*3*DM, QKV, nullptr, nullptr, MR, 3*DM, DM);
        attn_special_k<<<32, 128, 0, stream>>>(QKV, AO);
        rope_k<<<6272, 256, 0, stream>>>(QKV, fsin, fcos, 0);
        attn_main_k<<<dim3(32*NT, 1), 256, 0, stream>>>(QKV, AO, 0);
        gemm(AO, t_outW + (size_t)l*DM*DM, X, t_outb + l*DM, X, MR, DM, DM);

        // ---- space attention ----
        layernorm_k<<<MR, 256, 0, stream>>>(X, XN, ln_s_g + l*DM, ln_s_b + l*DM);
        gemm(XN, s_qkv + (size_t)l*DM*3*DM, QKV, nullptr, nullptr, MR, 3*DM, DM);
        attn_special_k<<<32, 128, 0, stream>>>(QKV, AO);
        rope_k<<<6272, 256, 0, stream>>>(QKV, isin, icos, 1);
        attn_main_k<<<dim3(32*NF, 13), 256, 0, stream>>>(QKV, AO, 1);
        gemm(AO, s_outW + (size_t)l*DM*DM, X, s_outb + l*DM, X, MR, DM, DM);

        // ---- GEGLU FF ----
        layernorm_k<<<MR, 256, 0, stream>>>(X, XN, ln_f_g + l*DM, ln_f_b + l*DM);
        gemm(XN, ff_W1 + (size_t)l*DM*8*DM, B1, ff_b1 + (size_t)l*8*DM, nullptr, MR, 8*DM, DM);
        geglu_k<<<(MR*2048 + 255)/256, 256, 0, stream>>>(B1, B2);
        gemm(B2, ff_W2 + (size_t)l*4*DM*DM, X, ff_b2 + l*DM, X, MR, DM, 4*DM);
    }

    final_head_k<<<NB, 256, 0, stream>>>(X, out_ln_g, out_ln_b, out_W, out_b, (float*)d_out);
}

// Round 3
// 14150.006 us; speedup vs baseline: 1.8626x; 1.8626x over previous
//
#include <hip/hip_runtime.h>
#include <math.h>

typedef __bf16 bf16;
typedef __bf16 bf16x8 __attribute__((ext_vector_type(8)));
typedef float  f32x4  __attribute__((ext_vector_type(4)));

#define SEQ   1570
#define NB    4
#define NF    8
#define NT    196
#define DM    512
#define MR    (NB*SEQ)   // 6280 rows

// ---------------------------------------------------------------------------
// Rotary tables
// ---------------------------------------------------------------------------
__global__ void build_rot_k(float* fsin, float* fcos, float* isin, float* icos)
{
    int tid = blockIdx.x * blockDim.x + threadIdx.x;
    if (tid < NF * 32) {
        int fi = tid >> 5, i = tid & 31;
        float inv = powf(10000.f, -(2.f * i) / 64.f);
        float v = fi * inv;
        float s = sinf(v), c = cosf(v);
        fsin[fi*64 + 2*i] = s; fsin[fi*64 + 2*i + 1] = s;
        fcos[fi*64 + 2*i] = c; fcos[fi*64 + 2*i + 1] = c;
    }
    if (tid < NT * 32) {
        int t = tid >> 5, i = tid & 31;
        int hi = t / 14, wi = t % 14;
        const float PI = 3.14159265358979323846f;
        float v;
        if (i < 16) {
            float scale = 1.f + 4.f * i / 15.f;
            v = (-1.f + 2.f * hi / 13.f) * scale * PI;
        } else {
            float scale = 1.f + 4.f * (i - 16) / 15.f;
            v = (-1.f + 2.f * wi / 13.f) * scale * PI;
        }
        float s = sinf(v), c = cosf(v);
        isin[t*64 + 2*i] = s; isin[t*64 + 2*i + 1] = s;
        icos[t*64 + 2*i] = c; icos[t*64 + 2*i + 1] = c;
    }
}

// ---------------------------------------------------------------------------
// Patchify: video (4,8,3,224,224) f32 -> VP (6272,768) bf16
// ---------------------------------------------------------------------------
__global__ void patch_gather_k(const float* __restrict__ video, bf16* __restrict__ VP)
{
    int idx = blockIdx.x * blockDim.x + threadIdx.x;
    if (idx >= NB * NF * NT * 768) return;
    int kk  = idx % 768;
    int row = (idx / 768) % (NF * NT);
    int b   = idx / (768 * NF * NT);
    int ch = kk % 3, pp = kk / 3;
    int pr = pp >> 4, pc = pp & 15;
    int fi = row / NT, t = row % NT;
    int hi = t / 14, wi = t % 14;
    size_t src = ((((size_t)b * NF + fi) * 3 + ch) * 224 + (hi*16 + pr)) * 224 + (wi*16 + pc);
    VP[idx] = (bf16)video[src];
}

// ---------------------------------------------------------------------------
// cls token + action-angle rows (fp32 X)
// ---------------------------------------------------------------------------
__global__ void init_special_k(float* X, const float* __restrict__ cls,
                               const float* __restrict__ aa_w,
                               const float* __restrict__ aa_W,
                               const float* __restrict__ aa_b)
{
    int idx = blockIdx.x * blockDim.x + threadIdx.x;
    if (idx >= NB * DM) return;
    int b = idx >> 9, d = idx & 511;
    X[(size_t)b * SEQ * DM + d] = cls[d];
    float acc = aa_b[d];
    for (int i = 0; i < 18; ++i) acc += aa_w[b*18 + i] * aa_W[i*DM + d];
    X[((size_t)b * SEQ + 1) * DM + d] = acc;
}

// ---------------------------------------------------------------------------
// Weight convert+transpose: W (L,K,N) f32 -> Wt (L,N,K) bf16
// ---------------------------------------------------------------------------
__global__ __launch_bounds__(256) void wconv_k(const float* __restrict__ W,
                                               bf16* __restrict__ Wt, int K, int N)
{
    __shared__ float t[32][33];
    int n0 = blockIdx.x * 32, k0 = blockIdx.y * 32;
    const float* Wl = W + (size_t)blockIdx.z * K * N;
    bf16* Wtl = Wt + (size_t)blockIdx.z * K * N;
    #pragma unroll
    for (int i = 0; i < 4; ++i) {
        int k = k0 + threadIdx.y + i*8;
        t[threadIdx.y + i*8][threadIdx.x] = Wl[(size_t)k * N + n0 + threadIdx.x];
    }
    __syncthreads();
    #pragma unroll
    for (int i = 0; i < 4; ++i) {
        int n = n0 + threadIdx.y + i*8;
        Wtl[(size_t)n * K + k0 + threadIdx.x] = (bf16)t[threadIdx.x][threadIdx.y + i*8];
    }
}

// ---------------------------------------------------------------------------
// MFMA GEMM: C[M,N] = A[M,K](bf16 row-major) * Bt[N,K](bf16 N-major)^T
// 128x128 block tile, BK=32, 4 waves (2x2), each wave 64x64 via 4x4
// mfma_f32_16x16x32_bf16. global_load_lds width=16 for both operands.
// Epilogue: +bias(f32), +resid(f32), store f32 (Cf) or bf16 (Cb); optional
// patch row remap. A rows clamped to M-1 (pad rows only pollute masked C rows).
// ---------------------------------------------------------------------------
__global__ __launch_bounds__(256) void gemm_mfma(
    const bf16* __restrict__ A, const bf16* __restrict__ Bt,
    float* __restrict__ Cf, bf16* __restrict__ Cb,
    const float* __restrict__ bias, const float* __restrict__ resid,
    int M, int N, int K, int remap)
{
    __shared__ bf16 As[128*32];
    __shared__ bf16 Bs[128*32];
    int tid  = threadIdx.x;
    int lane = tid & 63;
    int w    = tid >> 6;
    int wm = w >> 1, wn = w & 1;
    int rowBlk = blockIdx.y * 128, colBlk = blockIdx.x * 128;
    int lm = lane & 15, lq = lane >> 4;
    int sr  = lane >> 2;          // staging row within 16-row chunk
    int sc8 = (lane & 3) * 8;     // staging k-offset (elements)

    f32x4 acc[4][4];
    #pragma unroll
    for (int i = 0; i < 4; ++i)
        #pragma unroll
        for (int j = 0; j < 4; ++j) acc[i][j] = (f32x4){0.f, 0.f, 0.f, 0.f};

    for (int k0 = 0; k0 < K; k0 += 32) {
        #pragma unroll
        for (int c = 0; c < 2; ++c) {
            int ch = w*2 + c;                      // 16-row chunk 0..7
            int ar = rowBlk + ch*16 + sr;
            ar = (ar < M) ? ar : (M - 1);
            const bf16* ga = A + (size_t)ar * K + k0 + sc8;
            __builtin_amdgcn_global_load_lds(
                (const __attribute__((address_space(1))) unsigned int*)ga,
                (__attribute__((address_space(3))) unsigned int*)&As[ch*16*32],
                16, 0, 0);
            int br = colBlk + ch*16 + sr;
            const bf16* gb = Bt + (size_t)br * K + k0 + sc8;
            __builtin_amdgcn_global_load_lds(
                (const __attribute__((address_space(1))) unsigned int*)gb,
                (__attribute__((address_space(3))) unsigned int*)&Bs[ch*16*32],
                16, 0, 0);
        }
        __syncthreads();
        bf16x8 af[4], bfr[4];
        #pragma unroll
        for (int mt = 0; mt < 4; ++mt)
            af[mt] = *(const bf16x8*)&As[(wm*64 + mt*16 + lm)*32 + lq*8];
        #pragma unroll
        for (int nt = 0; nt < 4; ++nt)
            bfr[nt] = *(const bf16x8*)&Bs[(wn*64 + nt*16 + lm)*32 + lq*8];
        #pragma unroll
        for (int mt = 0; mt < 4; ++mt)
            #pragma unroll
            for (int nt = 0; nt < 4; ++nt)
                acc[mt][nt] = __builtin_amdgcn_mfma_f32_16x16x32_bf16(
                    af[mt], bfr[nt], acc[mt][nt], 0, 0, 0);
        __syncthreads();
    }

    #pragma unroll
    for (int nt = 0; nt < 4; ++nt) {
        int gn = colBlk + wn*64 + nt*16 + lm;
        float bs = bias ? bias[gn] : 0.f;
        #pragma unroll
        for (int mt = 0; mt < 4; ++mt) {
            #pragma unroll
            for (int r = 0; r < 4; ++r) {
                int gm = rowBlk + wm*64 + mt*16 + lq*4 + r;
                if (gm < M) {
                    int om = remap ? ((gm/1568)*1570 + 2 + (gm % 1568)) : gm;
                    size_t off = (size_t)om * N + gn;
                    float v = acc[mt][nt][r] + bs;
                    if (resid) v += resid[off];
                    if (Cf) Cf[off] = v;
                    else    Cb[off] = (bf16)v;
                }
            }
        }
    }
}

// ---------------------------------------------------------------------------
// LayerNorm: X fp32 -> XN bf16
// ---------------------------------------------------------------------------
__global__ __launch_bounds__(256) void layernorm_k(
    const float* __restrict__ X, bf16* __restrict__ XN,
    const float* __restrict__ g, const float* __restrict__ b)
{
    int row = blockIdx.x, tid = threadIdx.x;
    const float* x = X + (size_t)row * DM;
    float v0 = x[tid], v1 = x[tid + 256];
    __shared__ float r1[256], r2[256];
    r1[tid] = v0 + v1;
    r2[tid] = v0*v0 + v1*v1;
    __syncthreads();
    for (int off = 128; off > 0; off >>= 1) {
        if (tid < off) { r1[tid] += r1[tid+off]; r2[tid] += r2[tid+off]; }
        __syncthreads();
    }
    float mean = r1[0] * (1.f / DM);
    float var  = r2[0] * (1.f / DM) - mean * mean;
    float inv  = rsqrtf(var + 1e-5f);
    bf16* y = XN + (size_t)row * DM;
    y[tid]       = (bf16)((v0 - mean) * inv * g[tid]       + b[tid]);
    y[tid + 256] = (bf16)((v1 - mean) * inv * g[tid + 256] + b[tid + 256]);
}

// ---------------------------------------------------------------------------
// Special-token attention (pre-RoPE): q rows 0,1 over all 1570 k/v.
// One block per (b,h), 256 threads, LDS-tiled, parallel softmax.
// ---------------------------------------------------------------------------
__global__ __launch_bounds__(256) void attn_special_k(
    const bf16* __restrict__ QKV, bf16* __restrict__ AO)
{
    int bh = blockIdx.x;
    int b = bh >> 3, h = bh & 7;
    int tid = threadIdx.x;
    __shared__ float q2[2][64];
    __shared__ float sc[2][SEQ];
    __shared__ float kv[32][64];
    __shared__ float red[256];

    if (tid < 128) {
        int qi = tid >> 6, d = tid & 63;
        q2[qi][d] = (float)QKV[((size_t)(b*SEQ + qi))*1536 + h*64 + d] * 0.125f;
    }
    __syncthreads();

    // scores
    for (int kb = 0; kb < SEQ; kb += 32) {
        int rows = min(32, SEQ - kb);
        for (int i = tid; i < rows*64; i += 256) {
            int r = i >> 6, d = i & 63;
            kv[r][d] = (float)QKV[((size_t)(b*SEQ + kb + r))*1536 + 512 + h*64 + d];
        }
        __syncthreads();
        for (int i = tid; i < 2*rows; i += 256) {
            int qi = i & 1, r = i >> 1;
            float s = 0.f;
            #pragma unroll
            for (int d = 0; d < 64; ++d) s += q2[qi][d] * kv[r][d];
            sc[qi][kb + r] = s;
        }
        __syncthreads();
    }

    // softmax (two 128-thread groups, one per query row)
    {
        int qi = tid >> 7, t = tid & 127;
        float mx = -1e30f;
        for (int k = t; k < SEQ; k += 128) mx = fmaxf(mx, sc[qi][k]);
        red[tid] = mx; __syncthreads();
        for (int off = 64; off > 0; off >>= 1) {
            if (t < off) red[tid] = fmaxf(red[tid], red[tid + off]);
            __syncthreads();
        }
        mx = red[qi * 128];
        __syncthreads();
        float sum = 0.f;
        for (int k = t; k < SEQ; k += 128) {
            float e = expf(sc[qi][k] - mx); sc[qi][k] = e; sum += e;
        }
        red[tid] = sum; __syncthreads();
        for (int off = 64; off > 0; off >>= 1) {
            if (t < off) red[tid] += red[tid + off];
            __syncthreads();
        }
        float inv = 1.f / red[qi * 128];
        for (int k = t; k < SEQ; k += 128) sc[qi][k] *= inv;
    }
    __syncthreads();

    // AV
    float acc = 0.f;
    int aqi = tid >> 6, ad = tid & 63;     // valid for tid<128
    for (int kb = 0; kb < SEQ; kb += 32) {
        int rows = min(32, SEQ - kb);
        for (int i = tid; i < rows*64; i += 256) {
            int r = i >> 6, d = i & 63;
            kv[r][d] = (float)QKV[((size_t)(b*SEQ + kb + r))*1536 + 1024 + h*64 + d];
        }
        __syncthreads();
        if (tid < 128)
            for (int r = 0; r < rows; ++r) acc += sc[aqi][kb + r] * kv[r][ad];
        __syncthreads();
    }
    if (tid < 128)
        AO[((size_t)(b*SEQ + aqi))*DM + h*64 + ad] = (bf16)acc;
}

// ---------------------------------------------------------------------------
// In-place RoPE on q,k (bf16) for token rows >= 2
// ---------------------------------------------------------------------------
__global__ void rope_k(bf16* QKV, const float* __restrict__ sn,
                       const float* __restrict__ cs, int mode)
{
    int idx = blockIdx.x * blockDim.x + threadIdx.x;
    if (idx >= NB * NF * NT * 8 * 32) return;
    int p = idx & 31;
    int h = (idx >> 5) & 7;
    int t = (idx >> 8) % (NF * NT);
    int b = (idx >> 8) / (NF * NT);
    int ri = (mode == 0) ? (t / NT) : (t % NT);
    float c = cs[ri*64 + 2*p], s = sn[ri*64 + 2*p];
    size_t base = ((size_t)(b*SEQ + 2 + t)) * 1536 + h*64 + 2*p;
    float x0 = (float)QKV[base], x1 = (float)QKV[base + 1];
    QKV[base]     = (bf16)(x0 * c - x1 * s);
    QKV[base + 1] = (bf16)(x1 * c + x0 * s);
    base += 512;   // k
    x0 = (float)QKV[base]; x1 = (float)QKV[base + 1];
    QKV[base]     = (bf16)(x0 * c - x1 * s);
    QKV[base + 1] = (bf16)(x1 * c + x0 * s);
}

// ---------------------------------------------------------------------------
// Grouped attention (post-RoPE); kj<2 -> special rows 0,1.
// ---------------------------------------------------------------------------
__global__ __launch_bounds__(256) void attn_main_k(
    const bf16* __restrict__ QKV, bf16* __restrict__ AO, int mode)
{
    __shared__ float qs[16][68];
    __shared__ float ks[64][68];
    __shared__ float sc[16][208];
    int g = blockIdx.x, qt = blockIdx.y, tid = threadIdx.x;
    int bh, jj, fi, L, S;
    if (mode == 0) { bh = g / NT; jj = g % NT; fi = 0; L = NF; S = NF + 2; }
    else           { bh = g / NF; fi = g % NF; jj = 0; L = NT; S = NT + 2; }
    int b = bh >> 3, h = bh & 7;
    int q0 = qt * 16;

    for (int i = tid; i < 16*64; i += 256) {
        int qi = i >> 6, d = i & 63;
        int ql = q0 + qi;
        float v = 0.f;
        if (ql < L) {
            int s = (mode == 0) ? (2 + ql*NT + jj) : (2 + fi*NT + ql);
            v = (float)QKV[((size_t)(b*SEQ + s))*1536 + h*64 + d] * 0.125f;
        }
        qs[qi][d] = v;
    }
    __syncthreads();

    for (int kb = 0; kb < S; kb += 64) {
        int kc = min(64, S - kb);
        for (int i = tid; i < 64*64; i += 256) {
            int r = i >> 6, d = i & 63;
            float v = 0.f;
            int kj = kb + r;
            if (kj < S) {
                int s = (kj < 2) ? kj
                        : ((mode == 0) ? (2 + (kj-2)*NT + jj) : (2 + fi*NT + (kj-2)));
                v = (float)QKV[((size_t)(b*SEQ + s))*1536 + 512 + h*64 + d];
            }
            ks[r][d] = v;
        }
        __syncthreads();
        for (int i = tid; i < 16*64; i += 256) {
            int qi = i & 15, r = i >> 4;
            if (r < kc) {
                float s = 0.f;
                #pragma unroll
                for (int d = 0; d < 64; ++d) s += qs[qi][d] * ks[r][d];
                sc[qi][kb + r] = s;
            }
        }
        __syncthreads();
    }

    if (tid < 16) {
        float mx = -1e30f;
        for (int k = 0; k < S; ++k) mx = fmaxf(mx, sc[tid][k]);
        float sum = 0.f;
        for (int k = 0; k < S; ++k) { float e = expf(sc[tid][k] - mx); sc[tid][k] = e; sum += e; }
        float inv = 1.f / sum;
        for (int k = 0; k < S; ++k) sc[tid][k] *= inv;
    }
    __syncthreads();

    float acc[4] = {0.f, 0.f, 0.f, 0.f};
    int qi = tid >> 4, d0 = (tid & 15) * 4;
    for (int kb = 0; kb < S; kb += 64) {
        int kc = min(64, S - kb);
        for (int i = tid; i < 64*64; i += 256) {
            int r = i >> 6, d = i & 63;
            float v = 0.f;
            int kj = kb + r;
            if (kj < S) {
                int s = (kj < 2) ? kj
                        : ((mode == 0) ? (2 + (kj-2)*NT + jj) : (2 + fi*NT + (kj-2)));
                v = (float)QKV[((size_t)(b*SEQ + s))*1536 + 1024 + h*64 + d];
            }
            ks[r][d] = v;
        }
        __syncthreads();
        for (int r = 0; r < kc; ++r) {
            float p = sc[qi][kb + r];
            #pragma unroll
            for (int c = 0; c < 4; ++c) acc[c] += p * ks[r][d0 + c];
        }
        __syncthreads();
    }
    int ql = q0 + qi;
    if (ql < L) {
        int s = (mode == 0) ? (2 + ql*NT + jj) : (2 + fi*NT + ql);
        size_t off = ((size_t)(b*SEQ + s))*DM + h*64 + d0;
        #pragma unroll
        for (int c = 0; c < 4; ++c) AO[off + c] = (bf16)acc[c];
    }
}

// ---------------------------------------------------------------------------
// GEGLU: B2[m,i] = B1[m,i] * gelu_exact(B1[m,2048+i])   (bf16 io)
// ---------------------------------------------------------------------------
__global__ void geglu_k(const bf16* __restrict__ B1, bf16* __restrict__ B2)
{
    int idx = blockIdx.x * blockDim.x + threadIdx.x;
    if (idx >= MR * 2048) return;
    int m = idx / 2048;
    int i = idx % 2048;
    float a  = (float)B1[(size_t)m * 4096 + i];
    float gg = (float)B1[(size_t)m * 4096 + 2048 + i];
    float gl = 0.5f * gg * (1.f + erff(gg * 0.70710678118654752f));
    B2[idx] = (bf16)(a * gl);
}

// ---------------------------------------------------------------------------
// Final head: LN(x[:,0]) @ out_W (512,2) + out_b -> f32 out (4,2)
// ---------------------------------------------------------------------------
__global__ __launch_bounds__(256) void final_head_k(
    const float* __restrict__ X, const float* __restrict__ g, const float* __restrict__ bt,
    const float* __restrict__ W, const float* __restrict__ bo, float* __restrict__ out)
{
    int b = blockIdx.x, tid = threadIdx.x;
    const float* x = X + (size_t)b * SEQ * DM;
    float v0 = x[tid], v1 = x[tid + 256];
    __shared__ float r1[256], r2[256];
    r1[tid] = v0 + v1;
    r2[tid] = v0*v0 + v1*v1;
    __syncthreads();
    for (int off = 128; off > 0; off >>= 1) {
        if (tid < off) { r1[tid] += r1[tid+off]; r2[tid] += r2[tid+off]; }
        __syncthreads();
    }
    float mean = r1[0] * (1.f / DM);
    float var  = r2[0] * (1.f / DM) - mean * mean;
    float inv  = rsqrtf(var + 1e-5f);
    float xn0 = (v0 - mean) * inv * g[tid]       + bt[tid];
    float xn1 = (v1 - mean) * inv * g[tid + 256] + bt[tid + 256];
    __syncthreads();
    r1[tid] = xn0 * W[tid*2]     + xn1 * W[(tid+256)*2];
    r2[tid] = xn0 * W[tid*2 + 1] + xn1 * W[(tid+256)*2 + 1];
    __syncthreads();
    for (int off = 128; off > 0; off >>= 1) {
        if (tid < off) { r1[tid] += r1[tid+off]; r2[tid] += r2[tid+off]; }
        __syncthreads();
    }
    if (tid == 0) {
        out[b*2 + 0] = r1[0] + bo[0];
        out[b*2 + 1] = r2[0] + bo[1];
    }
}

// ---------------------------------------------------------------------------
extern "C" void kernel_launch(void* const* d_in, const int* in_sizes, int n_in,
                              void* d_out, int out_size, void* d_ws, size_t ws_size,
                              hipStream_t stream)
{
    const float* video    = (const float*)d_in[0];
    const float* aa_w     = (const float*)d_in[1];
    const float* patch_W  = (const float*)d_in[2];
    const float* patch_b  = (const float*)d_in[3];
    const float* cls_tok  = (const float*)d_in[4];
    const float* aa_W     = (const float*)d_in[5];
    const float* aa_b     = (const float*)d_in[6];
    const float* ln_t_g   = (const float*)d_in[7];
    const float* ln_t_b   = (const float*)d_in[8];
    const float* t_qkv    = (const float*)d_in[9];
    const float* t_outW   = (const float*)d_in[10];
    const float* t_outb   = (const float*)d_in[11];
    const float* ln_s_g   = (const float*)d_in[12];
    const float* ln_s_b   = (const float*)d_in[13];
    const float* s_qkv    = (const float*)d_in[14];
    const float* s_outW   = (const float*)d_in[15];
    const float* s_outb   = (const float*)d_in[16];
    const float* ln_f_g   = (const float*)d_in[17];
    const float* ln_f_b   = (const float*)d_in[18];
    const float* ff_W1    = (const float*)d_in[19];
    const float* ff_b1    = (const float*)d_in[20];
    const float* ff_W2    = (const float*)d_in[21];
    const float* ff_b2    = (const float*)d_in[22];
    const float* out_ln_g = (const float*)d_in[23];
    const float* out_ln_b = (const float*)d_in[24];
    const float* out_W    = (const float*)d_in[25];
    const float* out_b    = (const float*)d_in[26];

    // ---- workspace layout (223.2 MB total; round-2 proved >= 231.6 MB) ----
    char* p = (char*)d_ws;
    auto alloc = [&](size_t bytes) { char* r = p; p += (bytes + 255) & ~(size_t)255; return r; };
    float* X   = (float*)alloc((size_t)MR * DM * 4);        // residual, fp32
    bf16*  XN  = (bf16*)alloc((size_t)MR * DM * 2);         // LN out / attn out (AO)
    bf16*  R   = (bf16*)alloc((size_t)MR * 4096 * 2);       // QKV | B1 | VP (time-disjoint)
    bf16*  B2  = (bf16*)alloc((size_t)MR * 2048 * 2);       // geglu out
    bf16*  Wt  = (bf16*)alloc((size_t)63307776 * 2);        // transposed bf16 weights
    float* fsin = (float*)alloc(8*64*4);
    float* fcos = (float*)alloc(8*64*4);
    float* isin = (float*)alloc(196*64*4);
    float* icos = (float*)alloc(196*64*4);

    bf16* QKV = R;
    bf16* B1  = R;
    bf16* VP  = R;
    bf16* AO  = XN;

    bf16* patchW_t = Wt;                       // 512 x 768
    bf16* tqkv_t   = patchW_t + 393216;        // 12 x 1536 x 512
    bf16* toutW_t  = tqkv_t   + 9437184;       // 12 x 512 x 512
    bf16* sqkv_t   = toutW_t  + 3145728;
    bf16* soutW_t  = sqkv_t   + 9437184;
    bf16* ffW1_t   = soutW_t  + 3145728;       // 12 x 4096 x 512
    bf16* ffW2_t   = ffW1_t   + 25165824;      // 12 x 512 x 2048

    // ---- weight conversion (7 bulk launches) ----
    dim3 wb(32, 8);
    wconv_k<<<dim3(1536/32, 512/32, 12), wb, 0, stream>>>(t_qkv,  tqkv_t,  512, 1536);
    wconv_k<<<dim3( 512/32, 512/32, 12), wb, 0, stream>>>(t_outW, toutW_t, 512,  512);
    wconv_k<<<dim3(1536/32, 512/32, 12), wb, 0, stream>>>(s_qkv,  sqkv_t,  512, 1536);
    wconv_k<<<dim3( 512/32, 512/32, 12), wb, 0, stream>>>(s_outW, soutW_t, 512,  512);
    wconv_k<<<dim3(4096/32, 512/32, 12), wb, 0, stream>>>(ff_W1,  ffW1_t,  512, 4096);
    wconv_k<<<dim3( 512/32,2048/32, 12), wb, 0, stream>>>(ff_W2,  ffW2_t, 2048,  512);
    wconv_k<<<dim3( 512/32, 768/32,  1), wb, 0, stream>>>(patch_W, patchW_t, 768, 512);

    build_rot_k<<<25, 256, 0, stream>>>(fsin, fcos, isin, icos);

    // ---- patchify + token embedding ----
    patch_gather_k<<<(NB*NF*NT*768 + 255)/256, 256, 0, stream>>>(video, VP);
    init_special_k<<<(NB*DM + 255)/256, 256, 0, stream>>>(X, cls_tok, aa_w, aa_W, aa_b);
    gemm_mfma<<<dim3(512/128, 6272/128), 256, 0, stream>>>(
        VP, patchW_t, X, nullptr, patch_b, nullptr, 6272, 512, 768, 1);

    for (int l = 0; l < 12; ++l) {
        // ---- time attention ----
        layernorm_k<<<MR, 256, 0, stream>>>(X, XN, ln_t_g + l*DM, ln_t_b + l*DM);
        gemm_mfma<<<dim3(12, 50), 256, 0, stream>>>(
            XN, tqkv_t + (size_t)l*786432, nullptr, QKV, nullptr, nullptr, MR, 1536, 512, 0);
        attn_special_k<<<32, 256, 0, stream>>>(QKV, AO);
        rope_k<<<6272, 256, 0, stream>>>(QKV, fsin, fcos, 0);
        attn_main_k<<<dim3(32*NT, 1), 256, 0, stream>>>(QKV, AO, 0);
        gemm_mfma<<<dim3(4, 50), 256, 0, stream>>>(
            AO, toutW_t + (size_t)l*262144, X, nullptr, t_outb + l*DM, X, MR, 512, 512, 0);

        // ---- space attention ----
        layernorm_k<<<MR, 256, 0, stream>>>(X, XN, ln_s_g + l*DM, ln_s_b + l*DM);
        gemm_mfma<<<dim3(12, 50), 256, 0, stream>>>(
            XN, sqkv_t + (size_t)l*786432, nullptr, QKV, nullptr, nullptr, MR, 1536, 512, 0);
        attn_special_k<<<32, 256, 0, stream>>>(QKV, AO);
        rope_k<<<6272, 256, 0, stream>>>(QKV, isin, icos, 1);
        attn_main_k<<<dim3(32*NF, 13), 256, 0, stream>>>(QKV, AO, 1);
        gemm_mfma<<<dim3(4, 50), 256, 0, stream>>>(
            AO, soutW_t + (size_t)l*262144, X, nullptr, s_outb + l*DM, X, MR, 512, 512, 0);

        // ---- GEGLU FF ----
        layernorm_k<<<MR, 256, 0, stream>>>(X, XN, ln_f_g + l*DM, ln_f_b + l*DM);
        gemm_mfma<<<dim3(32, 50), 256, 0, stream>>>(
            XN, ffW1_t + (size_t)l*2097152, nullptr, B1, ff_b1 + (size_t)l*4096, nullptr, MR, 4096, 512, 0);
        geglu_k<<<(MR*2048 + 255)/256, 256, 0, stream>>>(B1, B2);
        gemm_mfma<<<dim3(4, 50), 256, 0, stream>>>(
            B2, ffW2_t + (size_t)l*1048576, X, nullptr, ff_b2 + l*DM, X, MR, 512, 2048, 0);
    }

    final_head_k<<<NB, 256, 0, stream>>>(X, out_ln_g, out_ln_b, out_W, out_b, (float*)d_out);
}

// Round 4
// 8435.200 us; speedup vs baseline: 3.1245x; 1.6775x over previous
//
#include <hip/hip_runtime.h>
#include <math.h>

typedef __bf16 bf16;
typedef __bf16 bf16x8 __attribute__((ext_vector_type(8)));
typedef float  f32x4  __attribute__((ext_vector_type(4)));

#define SEQ   1570
#define NB    4
#define NF    8
#define NT    196
#define DM    512
#define MR    (NB*SEQ)   // 6280 rows

// ---------------------------------------------------------------------------
// Rotary tables
// ---------------------------------------------------------------------------
__global__ void build_rot_k(float* fsin, float* fcos, float* isin, float* icos)
{
    int tid = blockIdx.x * blockDim.x + threadIdx.x;
    if (tid < NF * 32) {
        int fi = tid >> 5, i = tid & 31;
        float inv = powf(10000.f, -(2.f * i) / 64.f);
        float v = fi * inv;
        float s = sinf(v), c = cosf(v);
        fsin[fi*64 + 2*i] = s; fsin[fi*64 + 2*i + 1] = s;
        fcos[fi*64 + 2*i] = c; fcos[fi*64 + 2*i + 1] = c;
    }
    if (tid < NT * 32) {
        int t = tid >> 5, i = tid & 31;
        int hi = t / 14, wi = t % 14;
        const float PI = 3.14159265358979323846f;
        float v;
        if (i < 16) {
            float scale = 1.f + 4.f * i / 15.f;
            v = (-1.f + 2.f * hi / 13.f) * scale * PI;
        } else {
            float scale = 1.f + 4.f * (i - 16) / 15.f;
            v = (-1.f + 2.f * wi / 13.f) * scale * PI;
        }
        float s = sinf(v), c = cosf(v);
        isin[t*64 + 2*i] = s; isin[t*64 + 2*i + 1] = s;
        icos[t*64 + 2*i] = c; icos[t*64 + 2*i + 1] = c;
    }
}

// ---------------------------------------------------------------------------
// Patchify: video (4,8,3,224,224) f32 -> VP (6272,768) bf16
// ---------------------------------------------------------------------------
__global__ void patch_gather_k(const float* __restrict__ video, bf16* __restrict__ VP)
{
    int idx = blockIdx.x * blockDim.x + threadIdx.x;
    if (idx >= NB * NF * NT * 768) return;
    int kk  = idx % 768;
    int row = (idx / 768) % (NF * NT);
    int b   = idx / (768 * NF * NT);
    int ch = kk % 3, pp = kk / 3;
    int pr = pp >> 4, pc = pp & 15;
    int fi = row / NT, t = row % NT;
    int hi = t / 14, wi = t % 14;
    size_t src = ((((size_t)b * NF + fi) * 3 + ch) * 224 + (hi*16 + pr)) * 224 + (wi*16 + pc);
    VP[idx] = (bf16)video[src];
}

// ---------------------------------------------------------------------------
// cls token + action-angle rows (fp32 X)
// ---------------------------------------------------------------------------
__global__ void init_special_k(float* X, const float* __restrict__ cls,
                               const float* __restrict__ aa_w,
                               const float* __restrict__ aa_W,
                               const float* __restrict__ aa_b)
{
    int idx = blockIdx.x * blockDim.x + threadIdx.x;
    if (idx >= NB * DM) return;
    int b = idx >> 9, d = idx & 511;
    X[(size_t)b * SEQ * DM + d] = cls[d];
    float acc = aa_b[d];
    for (int i = 0; i < 18; ++i) acc += aa_w[b*18 + i] * aa_W[i*DM + d];
    X[((size_t)b * SEQ + 1) * DM + d] = acc;
}

// ---------------------------------------------------------------------------
// Weight convert+transpose: W (L,K,N) f32 -> Wt (L,N,K) bf16
// ---------------------------------------------------------------------------
__global__ __launch_bounds__(256) void wconv_k(const float* __restrict__ W,
                                               bf16* __restrict__ Wt, int K, int N)
{
    __shared__ float t[32][33];
    int n0 = blockIdx.x * 32, k0 = blockIdx.y * 32;
    const float* Wl = W + (size_t)blockIdx.z * K * N;
    bf16* Wtl = Wt + (size_t)blockIdx.z * K * N;
    #pragma unroll
    for (int i = 0; i < 4; ++i) {
        int k = k0 + threadIdx.y + i*8;
        t[threadIdx.y + i*8][threadIdx.x] = Wl[(size_t)k * N + n0 + threadIdx.x];
    }
    __syncthreads();
    #pragma unroll
    for (int i = 0; i < 4; ++i) {
        int n = n0 + threadIdx.y + i*8;
        Wtl[(size_t)n * K + k0 + threadIdx.x] = (bf16)t[threadIdx.x][threadIdx.y + i*8];
    }
}

// ---------------------------------------------------------------------------
// MFMA GEMM: C[M,N] = A[M,K](bf16 row-major) * Bt[N,K](bf16 N-major)^T
// 128x128 block tile, BK=32, 4 waves (2x2), each wave 64x64 via 4x4
// mfma_f32_16x16x32_bf16. global_load_lds width=16 for both operands.
// ---------------------------------------------------------------------------
__global__ __launch_bounds__(256) void gemm_mfma(
    const bf16* __restrict__ A, const bf16* __restrict__ Bt,
    float* __restrict__ Cf, bf16* __restrict__ Cb,
    const float* __restrict__ bias, const float* __restrict__ resid,
    int M, int N, int K, int remap)
{
    __shared__ bf16 As[128*32];
    __shared__ bf16 Bs[128*32];
    int tid  = threadIdx.x;
    int lane = tid & 63;
    int w    = tid >> 6;
    int wm = w >> 1, wn = w & 1;
    int rowBlk = blockIdx.y * 128, colBlk = blockIdx.x * 128;
    int lm = lane & 15, lq = lane >> 4;
    int sr  = lane >> 2;
    int sc8 = (lane & 3) * 8;

    f32x4 acc[4][4];
    #pragma unroll
    for (int i = 0; i < 4; ++i)
        #pragma unroll
        for (int j = 0; j < 4; ++j) acc[i][j] = (f32x4){0.f, 0.f, 0.f, 0.f};

    for (int k0 = 0; k0 < K; k0 += 32) {
        #pragma unroll
        for (int c = 0; c < 2; ++c) {
            int ch = w*2 + c;
            int ar = rowBlk + ch*16 + sr;
            ar = (ar < M) ? ar : (M - 1);
            const bf16* ga = A + (size_t)ar * K + k0 + sc8;
            __builtin_amdgcn_global_load_lds(
                (const __attribute__((address_space(1))) unsigned int*)ga,
                (__attribute__((address_space(3))) unsigned int*)&As[ch*16*32],
                16, 0, 0);
            int br = colBlk + ch*16 + sr;
            const bf16* gb = Bt + (size_t)br * K + k0 + sc8;
            __builtin_amdgcn_global_load_lds(
                (const __attribute__((address_space(1))) unsigned int*)gb,
                (__attribute__((address_space(3))) unsigned int*)&Bs[ch*16*32],
                16, 0, 0);
        }
        __syncthreads();
        bf16x8 af[4], bfr[4];
        #pragma unroll
        for (int mt = 0; mt < 4; ++mt)
            af[mt] = *(const bf16x8*)&As[(wm*64 + mt*16 + lm)*32 + lq*8];
        #pragma unroll
        for (int nt = 0; nt < 4; ++nt)
            bfr[nt] = *(const bf16x8*)&Bs[(wn*64 + nt*16 + lm)*32 + lq*8];
        #pragma unroll
        for (int mt = 0; mt < 4; ++mt)
            #pragma unroll
            for (int nt = 0; nt < 4; ++nt)
                acc[mt][nt] = __builtin_amdgcn_mfma_f32_16x16x32_bf16(
                    af[mt], bfr[nt], acc[mt][nt], 0, 0, 0);
        __syncthreads();
    }

    #pragma unroll
    for (int nt = 0; nt < 4; ++nt) {
        int gn = colBlk + wn*64 + nt*16 + lm;
        float bs = bias ? bias[gn] : 0.f;
        #pragma unroll
        for (int mt = 0; mt < 4; ++mt) {
            #pragma unroll
            for (int r = 0; r < 4; ++r) {
                int gm = rowBlk + wm*64 + mt*16 + lq*4 + r;
                if (gm < M) {
                    int om = remap ? ((gm/1568)*1570 + 2 + (gm % 1568)) : gm;
                    size_t off = (size_t)om * N + gn;
                    float v = acc[mt][nt][r] + bs;
                    if (resid) v += resid[off];
                    if (Cf) Cf[off] = v;
                    else    Cb[off] = (bf16)v;
                }
            }
        }
    }
}

// ---------------------------------------------------------------------------
// LayerNorm: X fp32 -> XN bf16
// ---------------------------------------------------------------------------
__global__ __launch_bounds__(256) void layernorm_k(
    const float* __restrict__ X, bf16* __restrict__ XN,
    const float* __restrict__ g, const float* __restrict__ b)
{
    int row = blockIdx.x, tid = threadIdx.x;
    const float* x = X + (size_t)row * DM;
    float v0 = x[tid], v1 = x[tid + 256];
    __shared__ float r1[256], r2[256];
    r1[tid] = v0 + v1;
    r2[tid] = v0*v0 + v1*v1;
    __syncthreads();
    for (int off = 128; off > 0; off >>= 1) {
        if (tid < off) { r1[tid] += r1[tid+off]; r2[tid] += r2[tid+off]; }
        __syncthreads();
    }
    float mean = r1[0] * (1.f / DM);
    float var  = r2[0] * (1.f / DM) - mean * mean;
    float inv  = rsqrtf(var + 1e-5f);
    bf16* y = XN + (size_t)row * DM;
    y[tid]       = (bf16)((v0 - mean) * inv * g[tid]       + b[tid]);
    y[tid + 256] = (bf16)((v1 - mean) * inv * g[tid + 256] + b[tid + 256]);
}

// ---------------------------------------------------------------------------
// Special-token attention, stage 1: scores.
// grid (32 bh, 13 chunks of 128 keys), 256 threads.
// SC[bh*2+qi][k] = (q_qi . k_k) * 0.125   (fp32)
// ---------------------------------------------------------------------------
__global__ __launch_bounds__(256) void sp_scores_k(
    const bf16* __restrict__ QKV, float* __restrict__ SC)
{
    int bh = blockIdx.x, ck = blockIdx.y;
    int b = bh >> 3, h = bh & 7;
    int tid = threadIdx.x;
    __shared__ float q2[2][64];
    __shared__ float kv[128][65];
    if (tid < 128) {
        int qi = tid >> 6, d = tid & 63;
        q2[qi][d] = (float)QKV[((size_t)(b*SEQ + qi))*1536 + h*64 + d] * 0.125f;
    }
    int k0 = ck * 128;
    int rows = min(128, SEQ - k0);
    for (int i = tid; i < rows*64; i += 256) {
        int r = i >> 6, d = i & 63;
        kv[r][d] = (float)QKV[((size_t)(b*SEQ + k0 + r))*1536 + 512 + h*64 + d];
    }
    __syncthreads();
    int qi = tid & 1, r = tid >> 1;
    if (r < rows) {
        float s = 0.f;
        #pragma unroll
        for (int d = 0; d < 64; ++d) s += q2[qi][d] * kv[r][d];
        SC[(size_t)(bh*2 + qi)*SEQ + k0 + r] = s;
    }
    if (tid >= 128) {   // second score slab: r in [128..) handled when rows>... (rows<=128, covered above)
    }
}

// ---------------------------------------------------------------------------
// Stage 2: softmax in place over SC rows of length 1570. grid 64 x 256 thr.
// ---------------------------------------------------------------------------
__global__ __launch_bounds__(256) void sp_softmax_k(float* __restrict__ SC)
{
    int row = blockIdx.x, tid = threadIdx.x;
    float* sc = SC + (size_t)row * SEQ;
    __shared__ float red[256];
    float mx = -1e30f;
    for (int k = tid; k < SEQ; k += 256) mx = fmaxf(mx, sc[k]);
    red[tid] = mx; __syncthreads();
    for (int off = 128; off > 0; off >>= 1) {
        if (tid < off) red[tid] = fmaxf(red[tid], red[tid + off]);
        __syncthreads();
    }
    mx = red[0]; __syncthreads();
    float sum = 0.f;
    for (int k = tid; k < SEQ; k += 256) {
        float e = expf(sc[k] - mx); sc[k] = e; sum += e;
    }
    red[tid] = sum; __syncthreads();
    for (int off = 128; off > 0; off >>= 1) {
        if (tid < off) red[tid] += red[tid + off];
        __syncthreads();
    }
    float inv = 1.f / red[0];
    for (int k = tid; k < SEQ; k += 256) sc[k] *= inv;
}

// ---------------------------------------------------------------------------
// Stage 3: AV partials. grid (32 bh, 2 qi, 8 chunks of 200), 256 thr
// (64 dims x 4 k-strides). PART[(bh*2+qi)*8 + ck][d]
// ---------------------------------------------------------------------------
__global__ __launch_bounds__(256) void sp_av_k(
    const bf16* __restrict__ QKV, const float* __restrict__ SC,
    float* __restrict__ PART)
{
    int bh = blockIdx.x, qi = blockIdx.y, ck = blockIdx.z;
    int b = bh >> 3, h = bh & 7;
    int tid = threadIdx.x;
    int d = tid & 63, kg = tid >> 6;
    int k0 = ck * 200;
    int kend = min(k0 + 200, SEQ);
    const float* sc = SC + (size_t)(bh*2 + qi)*SEQ;
    float acc = 0.f;
    for (int k = k0 + kg; k < kend; k += 4)
        acc += sc[k] * (float)QKV[((size_t)(b*SEQ + k))*1536 + 1024 + h*64 + d];
    __shared__ float red[256];
    red[tid] = acc; __syncthreads();
    if (kg == 0)
        PART[((size_t)(bh*2 + qi)*8 + ck)*64 + d] =
            red[d] + red[64 + d] + red[128 + d] + red[192 + d];
}

// ---------------------------------------------------------------------------
// Stage 4: reduce partials -> AO. grid 64 x 64 thr.
// ---------------------------------------------------------------------------
__global__ __launch_bounds__(64) void sp_avred_k(
    const float* __restrict__ PART, bf16* __restrict__ AO)
{
    int row = blockIdx.x;          // bh*2+qi
    int bh = row >> 1, qi = row & 1;
    int b = bh >> 3, h = bh & 7;
    int d = threadIdx.x;
    float s = 0.f;
    #pragma unroll
    for (int c = 0; c < 8; ++c) s += PART[((size_t)row*8 + c)*64 + d];
    AO[((size_t)(b*SEQ + qi))*DM + h*64 + d] = (bf16)s;
}

// ---------------------------------------------------------------------------
// In-place RoPE on q,k (bf16) for token rows >= 2
// ---------------------------------------------------------------------------
__global__ void rope_k(bf16* QKV, const float* __restrict__ sn,
                       const float* __restrict__ cs, int mode)
{
    int idx = blockIdx.x * blockDim.x + threadIdx.x;
    if (idx >= NB * NF * NT * 8 * 32) return;
    int p = idx & 31;
    int h = (idx >> 5) & 7;
    int t = (idx >> 8) % (NF * NT);
    int b = (idx >> 8) / (NF * NT);
    int ri = (mode == 0) ? (t / NT) : (t % NT);
    float c = cs[ri*64 + 2*p], s = sn[ri*64 + 2*p];
    size_t base = ((size_t)(b*SEQ + 2 + t)) * 1536 + h*64 + 2*p;
    float x0 = (float)QKV[base], x1 = (float)QKV[base + 1];
    QKV[base]     = (bf16)(x0 * c - x1 * s);
    QKV[base + 1] = (bf16)(x1 * c + x0 * s);
    base += 512;   // k
    x0 = (float)QKV[base]; x1 = (float)QKV[base + 1];
    QKV[base]     = (bf16)(x0 * c - x1 * s);
    QKV[base + 1] = (bf16)(x1 * c + x0 * s);
}

// ---------------------------------------------------------------------------
// Grouped attention (post-RoPE); kj<2 -> special rows 0,1.
// ---------------------------------------------------------------------------
__global__ __launch_bounds__(256) void attn_main_k(
    const bf16* __restrict__ QKV, bf16* __restrict__ AO, int mode)
{
    __shared__ float qs[16][68];
    __shared__ float ks[64][68];
    __shared__ float sc[16][208];
    int g = blockIdx.x, qt = blockIdx.y, tid = threadIdx.x;
    int bh, jj, fi, L, S;
    if (mode == 0) { bh = g / NT; jj = g % NT; fi = 0; L = NF; S = NF + 2; }
    else           { bh = g / NF; fi = g % NF; jj = 0; L = NT; S = NT + 2; }
    int b = bh >> 3, h = bh & 7;
    int q0 = qt * 16;

    for (int i = tid; i < 16*64; i += 256) {
        int qi = i >> 6, d = i & 63;
        int ql = q0 + qi;
        float v = 0.f;
        if (ql < L) {
            int s = (mode == 0) ? (2 + ql*NT + jj) : (2 + fi*NT + ql);
            v = (float)QKV[((size_t)(b*SEQ + s))*1536 + h*64 + d] * 0.125f;
        }
        qs[qi][d] = v;
    }
    __syncthreads();

    for (int kb = 0; kb < S; kb += 64) {
        int kc = min(64, S - kb);
        for (int i = tid; i < 64*64; i += 256) {
            int r = i >> 6, d = i & 63;
            float v = 0.f;
            int kj = kb + r;
            if (kj < S) {
                int s = (kj < 2) ? kj
                        : ((mode == 0) ? (2 + (kj-2)*NT + jj) : (2 + fi*NT + (kj-2)));
                v = (float)QKV[((size_t)(b*SEQ + s))*1536 + 512 + h*64 + d];
            }
            ks[r][d] = v;
        }
        __syncthreads();
        for (int i = tid; i < 16*64; i += 256) {
            int qi = i & 15, r = i >> 4;
            if (r < kc) {
                float s = 0.f;
                #pragma unroll
                for (int d = 0; d < 64; ++d) s += qs[qi][d] * ks[r][d];
                sc[qi][kb + r] = s;
            }
        }
        __syncthreads();
    }

    if (tid < 16) {
        float mx = -1e30f;
        for (int k = 0; k < S; ++k) mx = fmaxf(mx, sc[tid][k]);
        float sum = 0.f;
        for (int k = 0; k < S; ++k) { float e = expf(sc[tid][k] - mx); sc[tid][k] = e; sum += e; }
        float inv = 1.f / sum;
        for (int k = 0; k < S; ++k) sc[tid][k] *= inv;
    }
    __syncthreads();

    float acc[4] = {0.f, 0.f, 0.f, 0.f};
    int qi = tid >> 4, d0 = (tid & 15) * 4;
    for (int kb = 0; kb < S; kb += 64) {
        int kc = min(64, S - kb);
        for (int i = tid; i < 64*64; i += 256) {
            int r = i >> 6, d = i & 63;
            float v = 0.f;
            int kj = kb + r;
            if (kj < S) {
                int s = (kj < 2) ? kj
                        : ((mode == 0) ? (2 + (kj-2)*NT + jj) : (2 + fi*NT + (kj-2)));
                v = (float)QKV[((size_t)(b*SEQ + s))*1536 + 1024 + h*64 + d];
            }
            ks[r][d] = v;
        }
        __syncthreads();
        for (int r = 0; r < kc; ++r) {
            float p = sc[qi][kb + r];
            #pragma unroll
            for (int c = 0; c < 4; ++c) acc[c] += p * ks[r][d0 + c];
        }
        __syncthreads();
    }
    int ql = q0 + qi;
    if (ql < L) {
        int s = (mode == 0) ? (2 + ql*NT + jj) : (2 + fi*NT + ql);
        size_t off = ((size_t)(b*SEQ + s))*DM + h*64 + d0;
        #pragma unroll
        for (int c = 0; c < 4; ++c) AO[off + c] = (bf16)acc[c];
    }
}

// ---------------------------------------------------------------------------
// GEGLU: B2[m,i] = B1[m,i] * gelu_exact(B1[m,2048+i])   (bf16 io)
// ---------------------------------------------------------------------------
__global__ void geglu_k(const bf16* __restrict__ B1, bf16* __restrict__ B2)
{
    int idx = blockIdx.x * blockDim.x + threadIdx.x;
    if (idx >= MR * 2048) return;
    int m = idx / 2048;
    int i = idx % 2048;
    float a  = (float)B1[(size_t)m * 4096 + i];
    float gg = (float)B1[(size_t)m * 4096 + 2048 + i];
    float gl = 0.5f * gg * (1.f + erff(gg * 0.70710678118654752f));
    B2[idx] = (bf16)(a * gl);
}

// ---------------------------------------------------------------------------
// Final head: LN(x[:,0]) @ out_W (512,2) + out_b -> f32 out (4,2)
// ---------------------------------------------------------------------------
__global__ __launch_bounds__(256) void final_head_k(
    const float* __restrict__ X, const float* __restrict__ g, const float* __restrict__ bt,
    const float* __restrict__ W, const float* __restrict__ bo, float* __restrict__ out)
{
    int b = blockIdx.x, tid = threadIdx.x;
    const float* x = X + (size_t)b * SEQ * DM;
    float v0 = x[tid], v1 = x[tid + 256];
    __shared__ float r1[256], r2[256];
    r1[tid] = v0 + v1;
    r2[tid] = v0*v0 + v1*v1;
    __syncthreads();
    for (int off = 128; off > 0; off >>= 1) {
        if (tid < off) { r1[tid] += r1[tid+off]; r2[tid] += r2[tid+off]; }
        __syncthreads();
    }
    float mean = r1[0] * (1.f / DM);
    float var  = r2[0] * (1.f / DM) - mean * mean;
    float inv  = rsqrtf(var + 1e-5f);
    float xn0 = (v0 - mean) * inv * g[tid]       + bt[tid];
    float xn1 = (v1 - mean) * inv * g[tid + 256] + bt[tid + 256];
    __syncthreads();
    r1[tid] = xn0 * W[tid*2]     + xn1 * W[(tid+256)*2];
    r2[tid] = xn0 * W[tid*2 + 1] + xn1 * W[(tid+256)*2 + 1];
    __syncthreads();
    for (int off = 128; off > 0; off >>= 1) {
        if (tid < off) { r1[tid] += r1[tid+off]; r2[tid] += r2[tid+off]; }
        __syncthreads();
    }
    if (tid == 0) {
        out[b*2 + 0] = r1[0] + bo[0];
        out[b*2 + 1] = r2[0] + bo[1];
    }
}

// ---------------------------------------------------------------------------
extern "C" void kernel_launch(void* const* d_in, const int* in_sizes, int n_in,
                              void* d_out, int out_size, void* d_ws, size_t ws_size,
                              hipStream_t stream)
{
    const float* video    = (const float*)d_in[0];
    const float* aa_w     = (const float*)d_in[1];
    const float* patch_W  = (const float*)d_in[2];
    const float* patch_b  = (const float*)d_in[3];
    const float* cls_tok  = (const float*)d_in[4];
    const float* aa_W     = (const float*)d_in[5];
    const float* aa_b     = (const float*)d_in[6];
    const float* ln_t_g   = (const float*)d_in[7];
    const float* ln_t_b   = (const float*)d_in[8];
    const float* t_qkv    = (const float*)d_in[9];
    const float* t_outW   = (const float*)d_in[10];
    const float* t_outb   = (const float*)d_in[11];
    const float* ln_s_g   = (const float*)d_in[12];
    const float* ln_s_b   = (const float*)d_in[13];
    const float* s_qkv    = (const float*)d_in[14];
    const float* s_outW   = (const float*)d_in[15];
    const float* s_outb   = (const float*)d_in[16];
    const float* ln_f_g   = (const float*)d_in[17];
    const float* ln_f_b   = (const float*)d_in[18];
    const float* ff_W1    = (const float*)d_in[19];
    const float* ff_b1    = (const float*)d_in[20];
    const float* ff_W2    = (const float*)d_in[21];
    const float* ff_b2    = (const float*)d_in[22];
    const float* out_ln_g = (const float*)d_in[23];
    const float* out_ln_b = (const float*)d_in[24];
    const float* out_W    = (const float*)d_in[25];
    const float* out_b    = (const float*)d_in[26];

    // ---- workspace layout ----
    char* p = (char*)d_ws;
    auto alloc = [&](size_t bytes) { char* r = p; p += (bytes + 255) & ~(size_t)255; return r; };
    float* X   = (float*)alloc((size_t)MR * DM * 4);
    bf16*  XN  = (bf16*)alloc((size_t)MR * DM * 2);
    bf16*  R   = (bf16*)alloc((size_t)MR * 4096 * 2);
    bf16*  B2  = (bf16*)alloc((size_t)MR * 2048 * 2);
    bf16*  Wt  = (bf16*)alloc((size_t)63307776 * 2);
    float* SC  = (float*)alloc((size_t)64 * SEQ * 4);   // special-attn scores
    float* PART= (float*)alloc((size_t)64 * 8 * 64 * 4);// special-attn AV partials
    float* fsin = (float*)alloc(8*64*4);
    float* fcos = (float*)alloc(8*64*4);
    float* isin = (float*)alloc(196*64*4);
    float* icos = (float*)alloc(196*64*4);

    bf16* QKV = R;
    bf16* B1  = R;
    bf16* VP  = R;
    bf16* AO  = XN;

    bf16* patchW_t = Wt;
    bf16* tqkv_t   = patchW_t + 393216;
    bf16* toutW_t  = tqkv_t   + 9437184;
    bf16* sqkv_t   = toutW_t  + 3145728;
    bf16* soutW_t  = sqkv_t   + 9437184;
    bf16* ffW1_t   = soutW_t  + 3145728;
    bf16* ffW2_t   = ffW1_t   + 25165824;

    // ---- weight conversion ----
    dim3 wb(32, 8);
    wconv_k<<<dim3(1536/32, 512/32, 12), wb, 0, stream>>>(t_qkv,  tqkv_t,  512, 1536);
    wconv_k<<<dim3( 512/32, 512/32, 12), wb, 0, stream>>>(t_outW, toutW_t, 512,  512);
    wconv_k<<<dim3(1536/32, 512/32, 12), wb, 0, stream>>>(s_qkv,  sqkv_t,  512, 1536);
    wconv_k<<<dim3( 512/32, 512/32, 12), wb, 0, stream>>>(s_outW, soutW_t, 512,  512);
    wconv_k<<<dim3(4096/32, 512/32, 12), wb, 0, stream>>>(ff_W1,  ffW1_t,  512, 4096);
    wconv_k<<<dim3( 512/32,2048/32, 12), wb, 0, stream>>>(ff_W2,  ffW2_t, 2048,  512);
    wconv_k<<<dim3( 512/32, 768/32,  1), wb, 0, stream>>>(patch_W, patchW_t, 768, 512);

    build_rot_k<<<25, 256, 0, stream>>>(fsin, fcos, isin, icos);

    // ---- patchify + token embedding ----
    patch_gather_k<<<(NB*NF*NT*768 + 255)/256, 256, 0, stream>>>(video, VP);
    init_special_k<<<(NB*DM + 255)/256, 256, 0, stream>>>(X, cls_tok, aa_w, aa_W, aa_b);
    gemm_mfma<<<dim3(512/128, 6272/128), 256, 0, stream>>>(
        VP, patchW_t, X, nullptr, patch_b, nullptr, 6272, 512, 768, 1);

    auto attn_special = [&](bf16* qkv, bf16* ao) {
        sp_scores_k<<<dim3(32, 13), 256, 0, stream>>>(qkv, SC);
        sp_softmax_k<<<64, 256, 0, stream>>>(SC);
        sp_av_k<<<dim3(32, 2, 8), 256, 0, stream>>>(qkv, SC, PART);
        sp_avred_k<<<64, 64, 0, stream>>>(PART, ao);
    };

    for (int l = 0; l < 12; ++l) {
        // ---- time attention ----
        layernorm_k<<<MR, 256, 0, stream>>>(X, XN, ln_t_g + l*DM, ln_t_b + l*DM);
        gemm_mfma<<<dim3(12, 50), 256, 0, stream>>>(
            XN, tqkv_t + (size_t)l*786432, nullptr, QKV, nullptr, nullptr, MR, 1536, 512, 0);
        attn_special(QKV, AO);
        rope_k<<<6272, 256, 0, stream>>>(QKV, fsin, fcos, 0);
        attn_main_k<<<dim3(32*NT, 1), 256, 0, stream>>>(QKV, AO, 0);
        gemm_mfma<<<dim3(4, 50), 256, 0, stream>>>(
            AO, toutW_t + (size_t)l*262144, X, nullptr, t_outb + l*DM, X, MR, 512, 512, 0);

        // ---- space attention ----
        layernorm_k<<<MR, 256, 0, stream>>>(X, XN, ln_s_g + l*DM, ln_s_b + l*DM);
        gemm_mfma<<<dim3(12, 50), 256, 0, stream>>>(
            XN, sqkv_t + (size_t)l*786432, nullptr, QKV, nullptr, nullptr, MR, 1536, 512, 0);
        attn_special(QKV, AO);
        rope_k<<<6272, 256, 0, stream>>>(QKV, isin, icos, 1);
        attn_main_k<<<dim3(32*NF, 13), 256, 0, stream>>>(QKV, AO, 1);
        gemm_mfma<<<dim3(4, 50), 256, 0, stream>>>(
            AO, soutW_t + (size_t)l*262144, X, nullptr, s_outb + l*DM, X, MR, 512, 512, 0);

        // ---- GEGLU FF ----
        layernorm_k<<<MR, 256, 0, stream>>>(X, XN, ln_f_g + l*DM, ln_f_b + l*DM);
        gemm_mfma<<<dim3(32, 50), 256, 0, stream>>>(
            XN, ffW1_t + (size_t)l*2097152, nullptr, B1, ff_b1 + (size_t)l*4096, nullptr, MR, 4096, 512, 0);
        geglu_k<<<(MR*2048 + 255)/256, 256, 0, stream>>>(B1, B2);
        gemm_mfma<<<dim3(4, 50), 256, 0, stream>>>(
            B2, ffW2_t + (size_t)l*1048576, X, nullptr, ff_b2 + l*DM, X, MR, 512, 2048, 0);
    }

    final_head_k<<<NB, 256, 0, stream>>>(X, out_ln_g, out_ln_b, out_W, out_b, (float*)d_out);
}